// Round 6
// baseline (1907.979 us; speedup 1.0000x reference)
//
#include <hip/hip_runtime.h>
#include <hip/hip_bf16.h>

typedef unsigned short u16;
typedef unsigned int u32;
typedef __attribute__((ext_vector_type(4))) float f32x4;
typedef __attribute__((ext_vector_type(8))) short bf16x8;

#define N_NODES 16384
#define NDIM 256

__device__ __forceinline__ u16 f2b(float f) {
  // round-to-nearest-even fp32 -> bf16 (values are finite; no NaN handling needed)
  u32 u = __float_as_uint(f);
  u += 0x7fffu + ((u >> 16) & 1u);
  return (u16)(u >> 16);
}

// ---------------- kernel 1: deg row-sums -> dis = rsqrt(max(deg,eps)) ----------
__global__ __launch_bounds__(256) void k_deg(const float* __restrict__ adj,
                                             float* __restrict__ dis) {
  const int lane = threadIdx.x & 63;
  const int row  = blockIdx.x * 4 + (threadIdx.x >> 6);
  const float4* p = (const float4*)(adj + (size_t)row * N_NODES);
  float a0 = 0.f, a1 = 0.f, a2 = 0.f, a3 = 0.f;
  for (int i = 0; i < 64; i += 4) {
    float4 v0 = p[(i + 0) * 64 + lane];
    float4 v1 = p[(i + 1) * 64 + lane];
    float4 v2 = p[(i + 2) * 64 + lane];
    float4 v3 = p[(i + 3) * 64 + lane];
    a0 += v0.x + v0.y + v0.z + v0.w;
    a1 += v1.x + v1.y + v1.z + v1.w;
    a2 += v2.x + v2.y + v2.z + v2.w;
    a3 += v3.x + v3.y + v3.z + v3.w;
  }
  float s = (a0 + a1) + (a2 + a3);
  #pragma unroll
  for (int off = 32; off > 0; off >>= 1) s += __shfl_xor(s, off, 64);
  if (lane == 0) dis[row] = rsqrtf(fmaxf(s, 1e-12f));
}

// ---------------- kernel 2: build Fs (transposed, dis-scaled, pre-swizzled bf16)
//                  and Wt (transposed bf16 weight) ---------------------------
// Fs[n][kc*64 + s*8 + j] = bf16(feat[kc*64 + ((s^(n&7))*8+j)][n] * dis[...])
// so that a linear global_load_lds + XOR-swizzled ds_read is conflict-free.
__global__ __launch_bounds__(256) void k_prep(const float* __restrict__ feat,
                                              const float* __restrict__ weight,
                                              const float* __restrict__ dis,
                                              u16* __restrict__ Fs,
                                              u16* __restrict__ Wt) {
  const int t = threadIdx.x;
  if (blockIdx.x < 256) {
    const int kc = blockIdx.x;      // chunk of 64 graph nodes (k dimension)
    const int n  = t;               // feature column this thread owns
    const int x  = n & 7;
    u16* dst = Fs + (size_t)n * N_NODES + kc * 64;
    #pragma unroll
    for (int s = 0; s < 8; s++) {
      const int kb = kc * 64 + ((s ^ x) << 3);
      u16 b[8];
      #pragma unroll
      for (int j = 0; j < 8; j++) {
        const int k = kb + j;
        b[j] = f2b(feat[(size_t)k * NDIM + n] * dis[k]);
      }
      uint4 v;
      v.x = (u32)b[0] | ((u32)b[1] << 16);
      v.y = (u32)b[2] | ((u32)b[3] << 16);
      v.z = (u32)b[4] | ((u32)b[5] << 16);
      v.w = (u32)b[6] | ((u32)b[7] << 16);
      *(uint4*)(dst + s * 8) = v;
    }
  } else {
    // Wt[j][nk] = W[nk][j]
    const int j = t;
    for (int nb = 0; nb < 256; nb += 8) {
      u16 b[8];
      #pragma unroll
      for (int i = 0; i < 8; i++) b[i] = f2b(weight[(size_t)(nb + i) * NDIM + j]);
      uint4 v;
      v.x = (u32)b[0] | ((u32)b[1] << 16);
      v.y = (u32)b[2] | ((u32)b[3] << 16);
      v.z = (u32)b[4] | ((u32)b[5] << 16);
      v.w = (u32)b[6] | ((u32)b[7] << 16);
      *(uint4*)(Wt + (size_t)j * 256 + nb) = v;
    }
  }
}

// ---------------- kernel 3: x3 = dis .* (adj @ Fs^T), bf16 out ----------------
// block: 64 rows x 256 cols, 4 waves (each 64x64), BK=64, dbuf LDS (80 KB)
__global__ __launch_bounds__(256) void k_gemm1(const float* __restrict__ adj,
                                               const u16* __restrict__ Fs,
                                               const float* __restrict__ dis,
                                               u16* __restrict__ x3) {
  __shared__ u16 ldsA[2][64 * 64];    // [row][slot^ (row&7)] 8-elem slots, 8 KB each
  __shared__ u16 ldsB[2][256 * 64];   // [col][slot^ (col&7)] 32 KB each
  const int t   = threadIdx.x;
  const int w   = t >> 6;
  const int l   = t & 63;
  const int l15 = l & 15;
  const int lq  = l >> 4;
  const int lx  = l & 7;
  const int m0  = blockIdx.x * 64;
  // A-staging assignment: thread t handles rows (i*16 + tr), float4 chunk tc4
  const int tr  = t >> 4;             // 0..15
  const int tc4 = t & 15;             // 0..15 (4 floats each)
  const int aslotz = (tc4 >> 1) ^ (tr & 7);  // pre-swizzled 8-elem slot (row&7 == tr&7)

  f32x4 acc[4][4];
  #pragma unroll
  for (int mf = 0; mf < 4; mf++) {
    #pragma unroll
    for (int nf = 0; nf < 4; nf++) acc[mf][nf] = (f32x4){0.f, 0.f, 0.f, 0.f};
  }

  float4 areg[4];
  auto loadA = [&](int kt) {
    const float* base = adj + (size_t)(m0 + tr) * N_NODES + kt * 64 + tc4 * 4;
    #pragma unroll
    for (int i = 0; i < 4; i++)
      areg[i] = *(const float4*)(base + (size_t)i * 16 * N_NODES);
  };
  auto writeA = [&](int buf) {
    #pragma unroll
    for (int i = 0; i < 4; i++) {
      const int r = i * 16 + tr;
      u16* d = &ldsA[buf][r * 64 + (aslotz << 3) + ((tc4 & 1) << 2)];
      uint2 q;
      q.x = (u32)f2b(areg[i].x) | ((u32)f2b(areg[i].y) << 16);
      q.y = (u32)f2b(areg[i].z) | ((u32)f2b(areg[i].w) << 16);
      *(uint2*)d = q;
    }
  };
  auto issueB = [&](int kt, int buf) {
    #pragma unroll
    for (int c = 0; c < 8; c++) {
      const int nb = c * 32 + w * 8;                 // wave-uniform base row
      const u16* src = Fs + (size_t)(nb + (l >> 3)) * N_NODES + kt * 64 + (l & 7) * 8;
      __builtin_amdgcn_global_load_lds(
          (const __attribute__((address_space(1))) void*)src,
          (__attribute__((address_space(3))) void*)&ldsB[buf][nb * 64], 16, 0, 0);
    }
  };
  auto compute = [&](int buf) {
    #pragma unroll
    for (int h = 0; h < 2; h++) {
      const int slot = (((h << 2) + lq) ^ lx) << 3;
      bf16x8 af[4], bfr[4];
      #pragma unroll
      for (int mf = 0; mf < 4; mf++)
        af[mf] = *(const bf16x8*)&ldsA[buf][(mf * 16 + l15) * 64 + slot];
      #pragma unroll
      for (int nf = 0; nf < 4; nf++)
        bfr[nf] = *(const bf16x8*)&ldsB[buf][((w << 6) + nf * 16 + l15) * 64 + slot];
      #pragma unroll
      for (int mf = 0; mf < 4; mf++) {
        #pragma unroll
        for (int nf = 0; nf < 4; nf++)
          acc[mf][nf] = __builtin_amdgcn_mfma_f32_16x16x32_bf16(af[mf], bfr[nf],
                                                                acc[mf][nf], 0, 0, 0);
      }
    }
  };

  // prologue: stage tile 0
  issueB(0, 0);
  loadA(0);
  writeA(0);
  __syncthreads();

  for (int kt = 0; kt < 256; kt++) {
    const int cur = kt & 1;
    if (kt < 255) {
      issueB(kt + 1, cur ^ 1);
      loadA(kt + 1);
    }
    compute(cur);
    if (kt < 255) writeA(cur ^ 1);
    __syncthreads();
  }

  // epilogue: x3[row][col] = bf16(acc * dis[row])
  const int colb = (w << 6) + l15;
  #pragma unroll
  for (int mf = 0; mf < 4; mf++) {
    #pragma unroll
    for (int j = 0; j < 4; j++) {
      const int row = m0 + mf * 16 + (lq << 2) + j;
      const float dv = dis[row];
      u16* o = x3 + (size_t)row * NDIM + colb;
      #pragma unroll
      for (int nf = 0; nf < 4; nf++) o[nf * 16] = f2b(acc[mf][nf][j] * dv);
    }
  }
}

// ---------------- kernel 4: out = x3 @ W (frags straight from global) ---------
__global__ __launch_bounds__(256) void k_gemm2(const u16* __restrict__ x3,
                                               const u16* __restrict__ Wt,
                                               float* __restrict__ out) {
  const int t   = threadIdx.x;
  const int w   = t >> 6;
  const int l   = t & 63;
  const int l15 = l & 15;
  const int lq  = l >> 4;
  const int m0  = blockIdx.x * 64;

  f32x4 acc[4][4];
  #pragma unroll
  for (int mf = 0; mf < 4; mf++) {
    #pragma unroll
    for (int nf = 0; nf < 4; nf++) acc[mf][nf] = (f32x4){0.f, 0.f, 0.f, 0.f};
  }

  #pragma unroll
  for (int ks = 0; ks < 8; ks++) {
    bf16x8 af[4], bfr[4];
    #pragma unroll
    for (int mf = 0; mf < 4; mf++)
      af[mf] = *(const bf16x8*)(x3 + (size_t)(m0 + mf * 16 + l15) * NDIM + ks * 32 + lq * 8);
    #pragma unroll
    for (int nf = 0; nf < 4; nf++)
      bfr[nf] = *(const bf16x8*)(Wt + (size_t)((w << 6) + nf * 16 + l15) * NDIM + ks * 32 + lq * 8);
    #pragma unroll
    for (int mf = 0; mf < 4; mf++) {
      #pragma unroll
      for (int nf = 0; nf < 4; nf++)
        acc[mf][nf] = __builtin_amdgcn_mfma_f32_16x16x32_bf16(af[mf], bfr[nf],
                                                              acc[mf][nf], 0, 0, 0);
    }
  }

  #pragma unroll
  for (int mf = 0; mf < 4; mf++) {
    #pragma unroll
    for (int j = 0; j < 4; j++) {
      const int row = m0 + mf * 16 + (lq << 2) + j;
      float* o = out + (size_t)row * NDIM + (w << 6) + l15;
      #pragma unroll
      for (int nf = 0; nf < 4; nf++) o[nf * 16] = acc[mf][nf][j];
    }
  }
}

extern "C" void kernel_launch(void* const* d_in, const int* in_sizes, int n_in,
                              void* d_out, int out_size, void* d_ws, size_t ws_size,
                              hipStream_t stream) {
  const float* adj    = (const float*)d_in[0];
  const float* feat   = (const float*)d_in[1];
  const float* weight = (const float*)d_in[2];
  float* out = (float*)d_out;

  char* ws = (char*)d_ws;
  float* dis = (float*)ws;                                   //  64 KB
  u16*   Fs  = (u16*)(ws + 65536);                           //   8 MB
  u16*   Wt  = (u16*)(ws + 65536 + 8388608);                 // 128 KB
  u16*   x3  = (u16*)(ws + 65536 + 8388608 + 131072);        //   8 MB

  k_deg  <<<4096, 256, 0, stream>>>(adj, dis);
  k_prep <<<257,  256, 0, stream>>>(feat, weight, dis, Fs, Wt);
  k_gemm1<<<256,  256, 0, stream>>>(adj, Fs, dis, x3);
  k_gemm2<<<256,  256, 0, stream>>>(x3, Wt, out);
}